// Round 1
// baseline (179.635 us; speedup 1.0000x reference)
//
#include <hip/hip_runtime.h>

#define NDOF 7
#define BLK 256
#define STAGE (BLK * NDOF)

struct SConsts {
    float C0[NDOF][9];   // rot_fix[1+d]
    float C1[NDOF][9];   // rot_fix[1+d] @ K(axis)
    float C2[NDOF][9];   // rot_fix[1+d] @ K^2
    float p[NDOF][3];    // trans_fix[1+d]
    float ax[NDOF][3];   // joint_axes[d]
    float mass[NDOF];    // mass[1+d]
    float mc[NDOF][3];   // mass*com
    float Io[NDOF][9];   // inertia + m * cs*cs^T
    float damp[NDOF];
};

__device__ __forceinline__ void mat3mul(const float* A, const float* B, float* C) {
#pragma unroll
    for (int i = 0; i < 3; i++)
#pragma unroll
        for (int j = 0; j < 3; j++)
            C[i * 3 + j] = A[i * 3 + 0] * B[0 * 3 + j] + A[i * 3 + 1] * B[1 * 3 + j] +
                           A[i * 3 + 2] * B[2 * 3 + j];
}

__device__ __forceinline__ void cross3(const float* a, const float* b, float* o) {
    o[0] = a[1] * b[2] - a[2] * b[1];
    o[1] = a[2] * b[0] - a[0] * b[2];
    o[2] = a[0] * b[1] - a[1] * b[0];
}

__global__ __launch_bounds__(BLK) void rnea_kernel(
    const float* __restrict__ q_g, const float* __restrict__ qd_g,
    const float* __restrict__ qdd_g, const float* __restrict__ rot_fix,
    const float* __restrict__ trans_fix, const float* __restrict__ joint_axes,
    const float* __restrict__ mass_g, const float* __restrict__ com_g,
    const float* __restrict__ inertia_g, const float* __restrict__ damping_g,
    float* __restrict__ out, int n_elem) {
    __shared__ SConsts sc;
    __shared__ float sQ[STAGE], sQd[STAGE], sQdd[STAGE];

    const int t = threadIdx.x;

    // ---- per-block constant precompute (threads 0..6, one per dof) ----
    if (t < NDOF) {
        const int d = t;
        float F[9], K[9], C1[9], C2[9];
#pragma unroll
        for (int i = 0; i < 9; i++) F[i] = rot_fix[(1 + d) * 9 + i];
        const float ax0 = joint_axes[d * 3 + 0];
        const float ax1 = joint_axes[d * 3 + 1];
        const float ax2 = joint_axes[d * 3 + 2];
        K[0] = 0.f;  K[1] = -ax2; K[2] = ax1;
        K[3] = ax2;  K[4] = 0.f;  K[5] = -ax0;
        K[6] = -ax1; K[7] = ax0;  K[8] = 0.f;
        mat3mul(F, K, C1);
        mat3mul(C1, K, C2);
#pragma unroll
        for (int i = 0; i < 9; i++) {
            sc.C0[d][i] = F[i];
            sc.C1[d][i] = C1[i];
            sc.C2[d][i] = C2[i];
        }
#pragma unroll
        for (int i = 0; i < 3; i++) sc.p[d][i] = trans_fix[(1 + d) * 3 + i];
        sc.ax[d][0] = ax0; sc.ax[d][1] = ax1; sc.ax[d][2] = ax2;
        const float m = mass_g[1 + d];
        sc.mass[d] = m;
        const float c0 = com_g[(1 + d) * 3 + 0];
        const float c1 = com_g[(1 + d) * 3 + 1];
        const float c2 = com_g[(1 + d) * 3 + 2];
        sc.mc[d][0] = m * c0; sc.mc[d][1] = m * c1; sc.mc[d][2] = m * c2;
        float cs[9];
        cs[0] = 0.f; cs[1] = -c2; cs[2] = c1;
        cs[3] = c2;  cs[4] = 0.f; cs[5] = -c0;
        cs[6] = -c1; cs[7] = c0;  cs[8] = 0.f;
#pragma unroll
        for (int i = 0; i < 3; i++)
#pragma unroll
            for (int k = 0; k < 3; k++)
                sc.Io[d][i * 3 + k] =
                    inertia_g[(1 + d) * 9 + i * 3 + k] +
                    m * (cs[i * 3 + 0] * cs[k * 3 + 0] + cs[i * 3 + 1] * cs[k * 3 + 1] +
                         cs[i * 3 + 2] * cs[k * 3 + 2]);
        sc.damp[d] = damping_g[d];
    }

    // ---- coalesced staging of q, qd, qdd ----
    const int base = blockIdx.x * STAGE;
#pragma unroll
    for (int i = t; i < STAGE; i += BLK) {
        const int g = base + i;
        const bool ok = g < n_elem;
        sQ[i] = ok ? q_g[g] : 0.f;
        sQd[i] = ok ? qd_g[g] : 0.f;
        sQdd[i] = ok ? qdd_g[g] : 0.f;
    }
    __syncthreads();

    float q[NDOF], qd[NDOF], qdd[NDOF];
#pragma unroll
    for (int d = 0; d < NDOF; d++) {
        q[d] = sQ[t * NDOF + d];
        qd[d] = sQd[t * NDOF + d];
        qdd[d] = sQdd[t * NDOF + d];
    }

    float s_[NDOF], c_[NDOF];
    float fl[NDOF][3], fa[NDOF][3];
    float vl[3] = {0.f, 0.f, 0.f}, va[3] = {0.f, 0.f, 0.f};
    float al[3] = {0.f, 0.f, 9.81f}, aa[3] = {0.f, 0.f, 0.f};

    // ---- forward recursion + per-link force, fused ----
#pragma unroll
    for (int d = 0; d < NDOF; d++) {
        const float s = __sinf(q[d]);
        const float c = __cosf(q[d]);
        s_[d] = s; c_[d] = c;
        const float omc = 1.f - c;
        float R[9];
#pragma unroll
        for (int i = 0; i < 9; i++)
            R[i] = sc.C0[d][i] + s * sc.C1[d][i] + omc * sc.C2[d][i];

        const float px = sc.p[d][0], py = sc.p[d][1], pz = sc.p[d][2];
        float pinv[3];
        pinv[0] = -(R[0] * px + R[3] * py + R[6] * pz);
        pinv[1] = -(R[1] * px + R[4] * py + R[7] * pz);
        pinv[2] = -(R[2] * px + R[5] * py + R[8] * pz);

        float van[3], vln[3], aan[3], aln[3], tmp[3];
#pragma unroll
        for (int i = 0; i < 3; i++)
            van[i] = R[0 + i] * va[0] + R[3 + i] * va[1] + R[6 + i] * va[2];
#pragma unroll
        for (int i = 0; i < 3; i++)
            vln[i] = R[0 + i] * vl[0] + R[3 + i] * vl[1] + R[6 + i] * vl[2];
        cross3(pinv, van, tmp);
#pragma unroll
        for (int i = 0; i < 3; i++) vln[i] += tmp[i];
#pragma unroll
        for (int i = 0; i < 3; i++)
            aan[i] = R[0 + i] * aa[0] + R[3 + i] * aa[1] + R[6 + i] * aa[2];
#pragma unroll
        for (int i = 0; i < 3; i++)
            aln[i] = R[0 + i] * al[0] + R[3 + i] * al[1] + R[6 + i] * al[2];
        cross3(pinv, aan, tmp);
#pragma unroll
        for (int i = 0; i < 3; i++) aln[i] += tmp[i];

        const float jv[3] = {qd[d] * sc.ax[d][0], qd[d] * sc.ax[d][1], qd[d] * sc.ax[d][2]};
        const float ja[3] = {qdd[d] * sc.ax[d][0], qdd[d] * sc.ax[d][1], qdd[d] * sc.ax[d][2]};

#pragma unroll
        for (int i = 0; i < 3; i++) va[i] = van[i] + jv[i];
#pragma unroll
        for (int i = 0; i < 3; i++) vl[i] = vln[i];
        cross3(va, jv, tmp);
#pragma unroll
        for (int i = 0; i < 3; i++) aa[i] = aan[i] + ja[i] + tmp[i];
        cross3(vl, jv, tmp);
#pragma unroll
        for (int i = 0; i < 3; i++) al[i] = aln[i] + tmp[i];

        // spatial inertia products + bias force
        const float m = sc.mass[d];
        const float mc[3] = {sc.mc[d][0], sc.mc[d][1], sc.mc[d][2]};
        float Ial[3], Iaa[3], Ivl[3], Iva[3];
        cross3(aa, mc, tmp);
#pragma unroll
        for (int i = 0; i < 3; i++) Ial[i] = m * al[i] + tmp[i];
        cross3(mc, al, tmp);
#pragma unroll
        for (int i = 0; i < 3; i++)
            Iaa[i] = sc.Io[d][i * 3 + 0] * aa[0] + sc.Io[d][i * 3 + 1] * aa[1] +
                     sc.Io[d][i * 3 + 2] * aa[2] + tmp[i];
        cross3(va, mc, tmp);
#pragma unroll
        for (int i = 0; i < 3; i++) Ivl[i] = m * vl[i] + tmp[i];
        cross3(mc, vl, tmp);
#pragma unroll
        for (int i = 0; i < 3; i++)
            Iva[i] = sc.Io[d][i * 3 + 0] * va[0] + sc.Io[d][i * 3 + 1] * va[1] +
                     sc.Io[d][i * 3 + 2] * va[2] + tmp[i];

        cross3(va, Ivl, tmp);
#pragma unroll
        for (int i = 0; i < 3; i++) fl[d][i] = Ial[i] + tmp[i];
        float tmp2[3];
        cross3(va, Iva, tmp);
        cross3(vl, Ivl, tmp2);
#pragma unroll
        for (int i = 0; i < 3; i++) fa[d][i] = Iaa[i] + tmp[i] + tmp2[i];
    }

    // ---- backward recursion ----
    float cl[3] = {0.f, 0.f, 0.f}, ca[3] = {0.f, 0.f, 0.f};
    float tau[NDOF];
#pragma unroll
    for (int d = NDOF - 1; d >= 0; d--) {
        float tl[3], ta[3];
#pragma unroll
        for (int i = 0; i < 3; i++) { tl[i] = fl[d][i] + cl[i]; ta[i] = fa[d][i] + ca[i]; }
        tau[d] = ta[0] * sc.ax[d][0] + ta[1] * sc.ax[d][1] + ta[2] * sc.ax[d][2];

        const float s = s_[d];
        const float omc = 1.f - c_[d];
        float R[9];
#pragma unroll
        for (int i = 0; i < 9; i++)
            R[i] = sc.C0[d][i] + s * sc.C1[d][i] + omc * sc.C2[d][i];

        float nl[3], na[3], tmp[3];
#pragma unroll
        for (int i = 0; i < 3; i++)
            nl[i] = R[i * 3 + 0] * tl[0] + R[i * 3 + 1] * tl[1] + R[i * 3 + 2] * tl[2];
#pragma unroll
        for (int i = 0; i < 3; i++)
            na[i] = R[i * 3 + 0] * ta[0] + R[i * 3 + 1] * ta[1] + R[i * 3 + 2] * ta[2];
        cross3(sc.p[d], nl, tmp);
#pragma unroll
        for (int i = 0; i < 3; i++) { cl[i] = nl[i]; ca[i] = na[i] + tmp[i]; }
    }

    // ---- coalesced output staging (reuse sQ) ----
    __syncthreads();
#pragma unroll
    for (int d = 0; d < NDOF; d++) sQ[t * NDOF + d] = tau[d] + sc.damp[d] * qd[d];
    __syncthreads();
#pragma unroll
    for (int i = t; i < STAGE; i += BLK) {
        const int g = base + i;
        if (g < n_elem) out[g] = sQ[i];
    }
}

extern "C" void kernel_launch(void* const* d_in, const int* in_sizes, int n_in,
                              void* d_out, int out_size, void* d_ws, size_t ws_size,
                              hipStream_t stream) {
    const float* q = (const float*)d_in[0];
    const float* qd = (const float*)d_in[1];
    const float* qdd = (const float*)d_in[2];
    const float* rot_fix = (const float*)d_in[3];
    const float* trans_fix = (const float*)d_in[4];
    const float* joint_axes = (const float*)d_in[5];
    const float* mass = (const float*)d_in[6];
    const float* com = (const float*)d_in[7];
    const float* inertia = (const float*)d_in[8];
    const float* damping = (const float*)d_in[9];
    float* out = (float*)d_out;

    const int n_elem = in_sizes[0];           // B * 7
    const int B = n_elem / NDOF;
    const int grid = (B + BLK - 1) / BLK;

    rnea_kernel<<<grid, BLK, 0, stream>>>(q, qd, qdd, rot_fix, trans_fix, joint_axes,
                                          mass, com, inertia, damping, out, n_elem);
}